// Round 4
// baseline (108.180 us; speedup 1.0000x reference)
//
#include <hip/hip_runtime.h>

#define TEMP 10.0f
#define NS 4096
#define BB 512
#define DDIM 512
#define NCLS 10
#define LDSP 72

typedef short bf16x8 __attribute__((ext_vector_type(8)));
typedef float f32x4 __attribute__((ext_vector_type(4)));

__device__ inline short f2bf(float f) {
    unsigned u = __builtin_bit_cast(unsigned, f);
    u += 0x7FFFu + ((u >> 16) & 1u);      // round-to-nearest-even
    return (short)(u >> 16);
}
__device__ inline float bf2f(short h) {
    unsigned u = ((unsigned)(unsigned short)h) << 16;
    return __builtin_bit_cast(float, u);
}

// =============== prep: all conversions / norms / col0 extraction ===============
// blocks [0,1024)    : star rows -> Sb bf16 + sn2 + scol
// blocks [1024,1152) : x rows    -> Xb bf16 + xn2 + xcol (+ midx init on block 1024)
// blocks [1152,2176) : from rows -> Fb bf16 + fn2
// blocks [2176,2688) : from tiles -> FTb (bf16 transpose [DDIM][NS])
__global__ __launch_bounds__(256)
void prep(const float* __restrict__ x, const float* __restrict__ star,
          const float* __restrict__ from,
          short* __restrict__ Xb, short* __restrict__ Sb,
          short* __restrict__ FTb, short* __restrict__ Fb,
          float* __restrict__ xn2, float* __restrict__ sn2, float* __restrict__ fn2,
          float* __restrict__ scol, float* __restrict__ xcol, int* __restrict__ midx)
{
    int bid = blockIdx.x, t = threadIdx.x;
    if (bid < 2176) {
        const float* in; short* outb; float* n2; float* colb; int rowbase;
        if (bid < 1024)      { in = star; outb = Sb; n2 = sn2; colb = scol; rowbase = bid * 4; }
        else if (bid < 1152) { in = x;    outb = Xb; n2 = xn2; colb = xcol; rowbase = (bid - 1024) * 4; }
        else                 { in = from; outb = Fb; n2 = fn2; colb = nullptr; rowbase = (bid - 1152) * 4; }
        if (bid == 1024) { midx[t] = NS; midx[256 + t] = NS; }
        int row = rowbase + (t >> 6);
        int l = t & 63;
        const float4* p = (const float4*)(in + (size_t)row * DDIM) + l * 2;
        float4 a = p[0], b = p[1];
        float s = a.x*a.x + a.y*a.y + a.z*a.z + a.w*a.w
                + b.x*b.x + b.y*b.y + b.z*b.z + b.w*b.w;
        bf16x8 h;
        h[0]=f2bf(a.x); h[1]=f2bf(a.y); h[2]=f2bf(a.z); h[3]=f2bf(a.w);
        h[4]=f2bf(b.x); h[5]=f2bf(b.y); h[6]=f2bf(b.z); h[7]=f2bf(b.w);
        *(bf16x8*)(outb + (size_t)row * DDIM + l * 8) = h;
        #pragma unroll
        for (int off = 32; off > 0; off >>= 1) s += __shfl_down(s, off);
        if (l == 0) {
            n2[row] = s;
            if (colb) colb[row] = a.x;
        }
        return;
    }
    // ---- from transpose tile ----
    __shared__ short tile[64][LDSP];
    int tid2 = bid - 2176;
    int n0 = (tid2 & 63) * 64, d0 = (tid2 >> 6) * 64;
    int r = t >> 4, c4 = (t & 15) * 4;
    #pragma unroll
    for (int rr = 0; rr < 64; rr += 16) {
        float4 v = *(const float4*)(from + (size_t)(n0 + r + rr) * DDIM + d0 + c4);
        tile[r + rr][c4 + 0] = f2bf(v.x);
        tile[r + rr][c4 + 1] = f2bf(v.y);
        tile[r + rr][c4 + 2] = f2bf(v.z);
        tile[r + rr][c4 + 3] = f2bf(v.w);
    }
    __syncthreads();
    int dr = t >> 2, nco = (t & 3) * 16;
    short tmp[16];
    #pragma unroll
    for (int q = 0; q < 16; ++q) tmp[q] = tile[nco + q][dr];
    short* op = FTb + (size_t)(d0 + dr) * NS + n0 + nco;
    *(bf16x8*)op       = *(bf16x8*)tmp;
    *(bf16x8*)(op + 8) = *(bf16x8*)(tmp + 8);
}

// =============== MFMA GEMM  C[m][n] = sum_k A[m][k]*B[n][k] ===============
// BM=BN=64, BK=64, 4 waves (2x2), fragments 2x2/wave, double-buffered LDS.
// MODE 0: raw acc (K-split partial).  MODE 1: clamp(an2[m]+bn2[n]-2acc, 0).
// Blocks with gid >= ngemm perform the exact-match scan instead.
template<int MODE>
__global__ __launch_bounds__(256)
void gemm_bt(const short* __restrict__ A, const short* __restrict__ B, int K,
             int nshift, const float* __restrict__ an2, const float* __restrict__ bn2,
             float* __restrict__ C, int ldc, size_t cstride, int ngemm,
             const float* __restrict__ x, const float* __restrict__ star,
             const float* __restrict__ scol, const float* __restrict__ xcol,
             int* __restrict__ midx)
{
    __shared__ short As[2][64][LDSP];
    __shared__ short Bs[2][64][LDSP];
    int gid = blockIdx.x;
    int t = threadIdx.x;
    if (gid >= ngemm) {
        // ---------- exact-match role (8 blocks, 512 star rows each) ----------
        float* xl = (float*)&As[0][0][0];
        int mb = gid - ngemm;
        xl[t] = xcol[t]; xl[256 + t] = xcol[256 + t];
        __syncthreads();
        #pragma unroll
        for (int rep = 0; rep < 2; ++rep) {
            int n = mb * 512 + rep * 256 + t;
            float sv = scol[n];
            for (int b = 0; b < BB; ++b) {
                if (xl[b] == sv) {
                    const float* xr = x + (size_t)b * DDIM;
                    const float* sr = star + (size_t)n * DDIM;
                    bool eq = true;
                    for (int k = 0; k < DDIM && eq; k += 4) {
                        float4 xv = *(const float4*)(xr + k);
                        float4 s4 = *(const float4*)(sr + k);
                        eq = (xv.x == s4.x) && (xv.y == s4.y) &&
                             (xv.z == s4.z) && (xv.w == s4.w);
                    }
                    if (eq) atomicMin(&midx[b], n);
                }
            }
        }
        return;
    }
    int m0 = (gid & 7) << 6;
    int n0 = ((gid >> 3) & ((1 << nshift) - 1)) << 6;
    int z  = gid >> (3 + nshift);
    int kbase = z * 512;
    float* Cp = C + (size_t)z * cstride;
    int wid = t >> 6, lane = t & 63;
    int wr = wid >> 1, wc = wid & 1;
    int lr = lane & 15, lk = lane >> 4;

    int ar = t >> 2, ak = (t & 3) * 16;
    const short* Ag = A + (size_t)(m0 + ar) * K + kbase + ak;
    const short* Bg = B + (size_t)(n0 + ar) * K + kbase + ak;

    f32x4 acc[2][2] = {};
    bf16x8 ra0 = *(const bf16x8*)Ag;
    bf16x8 ra1 = *(const bf16x8*)(Ag + 8);
    bf16x8 rb0 = *(const bf16x8*)Bg;
    bf16x8 rb1 = *(const bf16x8*)(Bg + 8);
    int cur = 0;
    *(bf16x8*)&As[0][ar][ak]     = ra0;
    *(bf16x8*)&As[0][ar][ak + 8] = ra1;
    *(bf16x8*)&Bs[0][ar][ak]     = rb0;
    *(bf16x8*)&Bs[0][ar][ak + 8] = rb1;

    #pragma unroll
    for (int it = 0; it < 8; ++it) {
        __syncthreads();
        if (it + 1 < 8) {
            int ko = (it + 1) * 64;
            ra0 = *(const bf16x8*)(Ag + ko);
            ra1 = *(const bf16x8*)(Ag + ko + 8);
            rb0 = *(const bf16x8*)(Bg + ko);
            rb1 = *(const bf16x8*)(Bg + ko + 8);
        }
        #pragma unroll
        for (int ks = 0; ks < 2; ++ks) {
            int k0 = ks * 32 + lk * 8;
            bf16x8 af[2], bfr[2];
            #pragma unroll
            for (int i = 0; i < 2; ++i)
                af[i] = *(const bf16x8*)&As[cur][wr * 32 + i * 16 + lr][k0];
            #pragma unroll
            for (int j = 0; j < 2; ++j)
                bfr[j] = *(const bf16x8*)&Bs[cur][wc * 32 + j * 16 + lr][k0];
            #pragma unroll
            for (int i = 0; i < 2; ++i)
                #pragma unroll
                for (int j = 0; j < 2; ++j)
                    acc[i][j] = __builtin_amdgcn_mfma_f32_16x16x32_bf16(
                        af[i], bfr[j], acc[i][j], 0, 0, 0);
        }
        if (it + 1 < 8) {
            cur ^= 1;
            *(bf16x8*)&As[cur][ar][ak]     = ra0;
            *(bf16x8*)&As[cur][ar][ak + 8] = ra1;
            *(bf16x8*)&Bs[cur][ar][ak]     = rb0;
            *(bf16x8*)&Bs[cur][ar][ak + 8] = rb1;
        }
    }
    #pragma unroll
    for (int i = 0; i < 2; ++i) {
        #pragma unroll
        for (int r = 0; r < 4; ++r) {
            int gm = m0 + wr * 32 + i * 16 + lk * 4 + r;
            float a2 = (MODE == 1) ? an2[gm] : 0.0f;
            #pragma unroll
            for (int j = 0; j < 2; ++j) {
                int gn = n0 + wc * 32 + j * 16 + lr;
                float v = acc[i][j][r];
                if (MODE == 1) v = fmaxf(a2 + bn2[gn] - 2.0f * v, 0.0f);
                Cp[(size_t)gm * ldc + gn] = v;
            }
        }
    }
}

// =============== block-wide sum helper ===============
__device__ inline float block_sum(float s, float* red) {
    #pragma unroll
    for (int off = 32; off > 0; off >>= 1) s += __shfl_down(s, off);
    int wid = threadIdx.x >> 6;
    if ((threadIdx.x & 63) == 0) red[wid] = s;
    __syncthreads();
    float tot = red[0] + red[1] + red[2] + red[3];
    __syncthreads();
    return tot;
}

// =============== e = exp(-T*d/rowmean) -> bf16 eT + sumE ===============
__global__ __launch_bounds__(256)
void exp_rows(const float* __restrict__ dT, short* __restrict__ eT,
              float* __restrict__ sumE) {
    __shared__ float red[4];
    int b = blockIdx.x;
    int t = threadIdx.x;
    const float* row = dT + (size_t)b * NS;
    float4 v[4];
    float s = 0.f;
    #pragma unroll
    for (int q = 0; q < 4; ++q) {
        v[q] = *(const float4*)(row + t * 16 + q * 4);
        s += v[q].x + v[q].y + v[q].z + v[q].w;
    }
    float tot = block_sum(s, red);
    float scale = -TEMP * (float)NS / tot;
    float se = 0.f;
    bf16x8 h0, h1;
    #pragma unroll
    for (int q = 0; q < 4; ++q) {
        #pragma unroll
        for (int e = 0; e < 4; ++e) {
            float ev = __expf(v[q][e] * scale);
            short hh = f2bf(ev);
            se += bf2f(hh);
            if (q < 2) h0[q * 4 + e] = hh; else h1[(q - 2) * 4 + e] = hh;
        }
    }
    short* op = eT + (size_t)b * NS + t * 16;
    *(bf16x8*)op       = h0;
    *(bf16x8*)(op + 8) = h1;
    float setot = block_sum(se, red);
    if (t == 0) sumE[b] = setot;
}

// =============== xt = (sum_z wpart)/sumE (or matched row) -> bf16 + norm ===============
__global__ __launch_bounds__(256)
void xt_fin(const float* __restrict__ wpart, const float* __restrict__ sumE,
            const int* __restrict__ midx, const float* __restrict__ fromf,
            short* __restrict__ xtb, float* __restrict__ xtn2) {
    __shared__ float red[4];
    int b = blockIdx.x;
    int t = threadIdx.x;
    int d = t * 2;
    int mi = midx[b];
    float inv = 1.0f / sumE[b];
    float v0 = 0.f, v1 = 0.f;
    #pragma unroll
    for (int sl = 0; sl < 8; ++sl) {
        float2 p = *(const float2*)(wpart + (size_t)sl * (BB * DDIM) + (size_t)b * DDIM + d);
        v0 += p.x; v1 += p.y;
    }
    v0 *= inv; v1 *= inv;
    if (mi < NS) {
        v0 = fromf[(size_t)mi * DDIM + d];
        v1 = fromf[(size_t)mi * DDIM + d + 1];
    }
    xtb[(size_t)b * DDIM + d]     = f2bf(v0);
    xtb[(size_t)b * DDIM + d + 1] = f2bf(v1);
    float tot = block_sum(v0 * v0 + v1 * v1, red);
    if (t == 0) xtn2[b] = tot;
}

// =============== y_star row: softmax-weighted one-hot average ===============
__global__ __launch_bounds__(256)
void ystar(const float* __restrict__ d2T, const int* __restrict__ labels,
           float* __restrict__ out) {
    __shared__ float red[4];
    __shared__ float cred[NCLS + 1][4];
    int b = blockIdx.x;
    int t = threadIdx.x;
    const float* row = d2T + (size_t)b * NS;
    float4 v[4];
    float s = 0.f;
    #pragma unroll
    for (int q = 0; q < 4; ++q) {
        v[q] = *(const float4*)(row + t * 16 + q * 4);
        s += v[q].x + v[q].y + v[q].z + v[q].w;
    }
    float tot = block_sum(s, red);
    float scale = -TEMP * (float)NS / tot;
    float accs[NCLS] = {};
    float te = 0.f;
    #pragma unroll
    for (int q = 0; q < 4; ++q) {
        int4 lb = *(const int4*)(labels + t * 16 + q * 4);
        int lbl[4] = {lb.x, lb.y, lb.z, lb.w};
        #pragma unroll
        for (int e = 0; e < 4; ++e) {
            float ev = __expf(v[q][e] * scale);
            te += ev;
            #pragma unroll
            for (int c = 0; c < NCLS; ++c) accs[c] += (lbl[e] == c) ? ev : 0.f;
        }
    }
    int wid = t >> 6, lane = t & 63;
    #pragma unroll
    for (int c = 0; c < NCLS + 1; ++c) {
        float sv = (c < NCLS) ? accs[c] : te;
        #pragma unroll
        for (int off = 32; off > 0; off >>= 1) sv += __shfl_down(sv, off);
        if (lane == 0) cred[c][wid] = sv;
    }
    __syncthreads();
    if (t < NCLS) {
        float num = cred[t][0] + cred[t][1] + cred[t][2] + cred[t][3];
        float den = cred[NCLS][0] + cred[NCLS][1] + cred[NCLS][2] + cred[NCLS][3];
        out[b * NCLS + t] = num / den;
    }
}

extern "C" void kernel_launch(void* const* d_in, const int* in_sizes, int n_in,
                              void* d_out, int out_size, void* d_ws, size_t ws_size,
                              hipStream_t stream) {
    const float* x     = (const float*)d_in[0];
    const float* star  = (const float*)d_in[1];
    const float* from  = (const float*)d_in[2];
    const int*   label = (const int*)d_in[3];
    float* out = (float*)d_out;

    float* F = (float*)d_ws;                   // ws_size = 256 MiB; we use ~43 MB
    float* dT    = F;                          // [512][4096] f32   (8 MB)
    float* wpart = F + 2097152;                // 8 x [512][512] f32 (8 MB)
    float* d2T   = F + 4194304;                // [512][4096] f32   (8 MB)
    short* Sb    = (short*)(F + 6291456);      // star bf16  [4096][512]  (4 MB)
    short* FTb   = (short*)(F + 7340032);      // fromT bf16 [512][4096]  (4 MB)
    short* Fb    = (short*)(F + 8388608);      // from bf16  [4096][512]  (4 MB)
    short* Eb    = (short*)(F + 9437184);      // eT bf16    [512][4096]  (4 MB)
    short* Xb    = (short*)(F + 10485760);     // x bf16     [512][512]
    short* XTb   = (short*)(F + 10616832);     // xt bf16    [512][512]
    float* sn2   = F + 10747904;               // 4096
    float* fn2   = F + 10752000;               // 4096
    float* xn2   = F + 10756096;               // 512
    float* xtn2  = F + 10756608;               // 512
    float* sumE  = F + 10757120;               // 512
    float* scol  = F + 10757632;               // 4096
    float* xcol  = F + 10761728;               // 512
    int*   midx  = (int*)(F + 10762240);       // 512

    prep<<<2688, 256, 0, stream>>>(x, star, from, Xb, Sb, FTb, Fb,
                                   xn2, sn2, fn2, scol, xcol, midx);
    // dT[b][n] = clamp(|x_b|^2+|star_n|^2-2 x.star, 0)  + 8 match blocks
    gemm_bt<1><<<520, 256, 0, stream>>>(Xb, Sb, DDIM, 6, xn2, sn2, dT, NS, 0,
                                        512, x, star, scol, xcol, midx);
    exp_rows<<<BB, 256, 0, stream>>>(dT, Eb, sumE);
    // wpart[z][b][d] = sum_{n in slab z} eT[b][n]*fromT[d][n]
    gemm_bt<0><<<512, 256, 0, stream>>>(Eb, FTb, NS, 3, nullptr, nullptr, wpart,
                                        DDIM, (size_t)BB * DDIM,
                                        512, nullptr, nullptr, nullptr, nullptr, nullptr);
    xt_fin<<<BB, 256, 0, stream>>>(wpart, sumE, midx, from, XTb, xtn2);
    // d2T[b][n] = clamp(|xt_b|^2+|from_n|^2-2 xt.from, 0)
    gemm_bt<1><<<512, 256, 0, stream>>>(XTb, Fb, DDIM, 6, xtn2, fn2, d2T, NS, 0,
                                        512, nullptr, nullptr, nullptr, nullptr, nullptr);
    ystar<<<BB, 256, 0, stream>>>(d2T, label, out);
}